// Round 6
// baseline (207.891 us; speedup 1.0000x reference)
//
#include <hip/hip_runtime.h>
#include <math.h>

#define IH 1024
#define IW 1024
#define NPIX (IH * IW)

// ---------------- Stage 1+2+3 fused: gray -> Sobel -> NMS -> bit-packed ----------
// Block = 256 threads = 4 waves; tile = 16 rows x 64 cols.  Each wave's 64 lanes
// are one row of 64 columns, so __ballot emits the u64 row-word directly.
__global__ __launch_bounds__(256) void k_fused(const float* __restrict__ x,
                                               unsigned long long* __restrict__ Sp,
                                               unsigned long long* __restrict__ Wp) {
    __shared__ float g[20][72];   // gray tile, origin (-2,-2) of interior
    __shared__ float m[18][68];   // mag tile,  origin (-1,-1) of interior
    const int bx = blockIdx.x & 15, by = blockIdx.x >> 4;
    const int tid = threadIdx.x;
    const int gi0 = by * 16 - 2, gj0 = bx * 64 - 2;

    for (int e = tid; e < 20 * 68; e += 256) {
        int ly = e / 68, lx = e - ly * 68;
        int gy = gi0 + ly, gxc = gj0 + lx;
        float v = 0.f;
        if ((unsigned)gy < (unsigned)IH && (unsigned)gxc < (unsigned)IW) {
            int p = gy * IW + gxc;
            float r = x[p], gg = x[NPIX + p], b = x[2 * NPIX + p];
            v = __fadd_rn(__fadd_rn(__fmul_rn(r, 0.2989f), __fmul_rn(gg, 0.587f)),
                          __fmul_rn(b, 0.114f));
        }
        g[ly][lx] = v;
    }
    __syncthreads();

    for (int e = tid; e < 18 * 66; e += 256) {
        int ly = e / 66, lx = e - ly * 66;
        float a00 = g[ly][lx],   a01 = g[ly][lx+1],   a02 = g[ly][lx+2];
        float a10 = g[ly+1][lx],                      a12 = g[ly+1][lx+2];
        float a20 = g[ly+2][lx], a21 = g[ly+2][lx+1], a22 = g[ly+2][lx+2];
        float gx = __fmul_rn(-1.f, a00);
        gx = __fadd_rn(gx, a02);
        gx = __fadd_rn(gx, __fmul_rn(-2.f, a10));
        gx = __fadd_rn(gx, __fmul_rn(2.f, a12));
        gx = __fadd_rn(gx, __fmul_rn(-1.f, a20));
        gx = __fadd_rn(gx, a22);
        float gy = a00;
        gy = __fadd_rn(gy, __fmul_rn(2.f, a01));
        gy = __fadd_rn(gy, a02);
        gy = __fadd_rn(gy, __fmul_rn(-1.f, a20));
        gy = __fadd_rn(gy, __fmul_rn(-2.f, a21));
        gy = __fadd_rn(gy, __fmul_rn(-1.f, a22));
        m[ly][lx] = __fsqrt_rn(__fadd_rn(__fmul_rn(gx, gx), __fmul_rn(gy, gy)));
    }
    __syncthreads();

    const int lane = tid & 63;
    const int wv = tid >> 6;
    #pragma unroll
    for (int rr = 0; rr < 4; ++rr) {
        int ti = wv * 4 + rr;
        int i = by * 16 + ti, j = bx * 64 + lane;
        float a00 = g[ti+1][lane+1], a01 = g[ti+1][lane+2], a02 = g[ti+1][lane+3];
        float a10 = g[ti+2][lane+1],                         a12 = g[ti+2][lane+3];
        float a20 = g[ti+3][lane+1], a21 = g[ti+3][lane+2], a22 = g[ti+3][lane+3];
        float gx = __fmul_rn(-1.f, a00);
        gx = __fadd_rn(gx, a02);
        gx = __fadd_rn(gx, __fmul_rn(-2.f, a10));
        gx = __fadd_rn(gx, __fmul_rn(2.f, a12));
        gx = __fadd_rn(gx, __fmul_rn(-1.f, a20));
        gx = __fadd_rn(gx, a22);
        float gy = a00;
        gy = __fadd_rn(gy, __fmul_rn(2.f, a01));
        gy = __fadd_rn(gy, a02);
        gy = __fadd_rn(gy, __fmul_rn(-1.f, a20));
        gy = __fadd_rn(gy, __fmul_rn(-2.f, a21));
        gy = __fadd_rn(gy, __fmul_rn(-1.f, a22));

        float ai = __fmul_rn(atan2f(gy, gx), 57.295779513082320876798154814105f);
        float c = m[ti+1][lane+1];
        float n1, n2;
        if (ai < -22.5f || ai >= 157.5f)      { n1 = m[ti+1][lane];   n2 = m[ti+1][lane+2]; }
        else if (ai < 22.5f)                  { n1 = m[ti][lane+1];   n2 = m[ti+2][lane+1]; }
        else if (ai < 67.5f)                  { n1 = m[ti][lane];     n2 = m[ti+2][lane+2]; }
        else if (ai < 112.5f)                 { n1 = m[ti][lane+1];   n2 = m[ti+2][lane+1]; }
        else                                  { n1 = m[ti][lane+2];   n2 = m[ti+2][lane];   }
        bool border = (i == 0) | (i == IH - 1) | (j == 0) | (j == IW - 1);
        bool keep = (c >= n1) && (c >= n2);
        float supp = keep ? c : 0.f;
        bool sb = !border && (supp >= 50.f);
        bool wb = !border && (supp >= 20.f) && !(supp >= 50.f);
        unsigned long long bs = __ballot(sb);
        unsigned long long bw = __ballot(wb);
        if (lane == 0) {
            Sp[i * 16 + bx] = bs;
            Wp[i * 16 + bx] = bw;
        }
    }
}

// Opaque load: the empty asm hides the pointer's provenance, so the compiler
// cannot prove the load doesn't alias the in-loop Sp stores -> it can neither
// sink nor rematerialize it -> the value stays live in a VGPR (real prefetch).
__device__ __forceinline__ unsigned int oload(const unsigned int* p, int off, int k) {
    const unsigned int* q = p + off;
    asm volatile("" : "+s"(q));
    return q[k];
}

// ---------------- Stage 4: single-wave tracker ----------------
#define TRACK_BODY(d, SRD, SWR, WRD) {                                          \
    const int i = base + d;                                                     \
    /* ---- serial chain head ---- */                                           \
    unsigned int hxp = (prevU << 1) | prevU | ((prevU >> 1) | crp);             \
    unsigned int seed = hxp | STAT;                                             \
    unsigned int P = WRD;                                                       \
    unsigned int G = SCc | (P & seed);                                          \
    unsigned int A = G | P;                                                     \
    unsigned int AXG = A ^ G;                                                   \
    unsigned int s1v = A + G;                                                   \
    unsigned long long gm = __ballot(s1v < A) & 0xFFFFFFFFull;                  \
    unsigned long long pm = __ballot(s1v == 0xFFFFFFFFu) & 0xFFFFFFFFull;       \
    unsigned long long G0 = __ballot((G & 1u) != 0u);                           \
    unsigned long long P0 = __ballot((P & 1u) != 0u);                           \
    __builtin_amdgcn_sched_barrier(0);                                          \
    /* ---- independent: next row's static seed + prefetch + store ---- */      \
    unsigned int SN2 = SRD;                                                     \
    unsigned long long mhi = __ballot((SN2 >> 31) != 0u);                       \
    unsigned long long mlo2 = __ballot((SN2 & 1u) != 0u);                       \
    unsigned int ltN = (((unsigned int)(mhi << 1)) >> k) & 1u;                  \
    unsigned int rtN = ((((unsigned int)(mlo2 >> 1)) >> k) & 1u) << 31;         \
    unsigned int rxN = SN2 | (SN2 >> 1) | rtN;                                  \
    unsigned int hxN = rxN | (SN2 << 1) | ltN;                                  \
    unsigned int nSTAT = rxA | hxN;                                             \
    { int srow = i + 17; if (srow > 1023) srow = 1023;                          \
      int wrow = i + 16; if (wrow > 1023) wrow = 1023;                          \
      SWR = oload(Sp, srow * 32, k);                                            \
      WRD = oload(Wp, wrow * 32, k); }                                          \
    if (i >= 2 && i <= 1023) Sp[(i - 1) * 32 + k] = prevU;                      \
    __builtin_amdgcn_sched_barrier(0);                                          \
    /* ---- resolve cross-word carries ---- */                                  \
    unsigned long long aa = gm | pm;                                            \
    unsigned long long ssum = aa + gm;                                          \
    unsigned long long cvw = ssum ^ aa ^ gm;                                    \
    unsigned long long mlo_o = G0 | (P0 & cvw);                                 \
    unsigned int cin = (((unsigned int)cvw) >> k) & 1u;                         \
    unsigned int ovb = ((((unsigned int)(cvw >> 1)) >> k) & 1u) << 31;          \
    unsigned int s2 = s1v + cin;                                                \
    unsigned int outv = ((s2 ^ AXG) >> 1) | ovb;                                \
    unsigned int rtP = ((((unsigned int)(mlo_o >> 1)) >> k) & 1u) << 31;        \
    crp = cin | rtP;                                                            \
    prevU = outv;                                                               \
    SCc = SA; SA = SN2; STAT = nSTAT; rxA = rxN;                                \
}

__global__ __launch_bounds__(64) void k_track(unsigned int* __restrict__ Sp,
                                              const unsigned int* __restrict__ Wp) {
    const int k = threadIdx.x & 31;

    unsigned int ss0, ss1, ss2, ss3, ss4, ss5, ss6, ss7,
                 ss8, ss9, ss10, ss11, ss12, ss13, ss14, ss15;
    unsigned int ww0, ww1, ww2, ww3, ww4, ww5, ww6, ww7,
                 ww8, ww9, ww10, ww11, ww12, ww13, ww14, ww15;

    unsigned int SCc = oload(Sp, 1 * 32, k);
    unsigned int SA  = oload(Sp, 2 * 32, k);
    ss3 = oload(Sp, 3 * 32, k);   ss4 = oload(Sp, 4 * 32, k);
    ss5 = oload(Sp, 5 * 32, k);   ss6 = oload(Sp, 6 * 32, k);
    ss7 = oload(Sp, 7 * 32, k);   ss8 = oload(Sp, 8 * 32, k);
    ss9 = oload(Sp, 9 * 32, k);   ss10 = oload(Sp, 10 * 32, k);
    ss11 = oload(Sp, 11 * 32, k); ss12 = oload(Sp, 12 * 32, k);
    ss13 = oload(Sp, 13 * 32, k); ss14 = oload(Sp, 14 * 32, k);
    ss15 = oload(Sp, 15 * 32, k); ss0 = oload(Sp, 16 * 32, k);
    ss1 = oload(Sp, 17 * 32, k);  ss2 = 0u;
    ww1 = oload(Wp, 1 * 32, k);   ww2 = oload(Wp, 2 * 32, k);
    ww3 = oload(Wp, 3 * 32, k);   ww4 = oload(Wp, 4 * 32, k);
    ww5 = oload(Wp, 5 * 32, k);   ww6 = oload(Wp, 6 * 32, k);
    ww7 = oload(Wp, 7 * 32, k);   ww8 = oload(Wp, 8 * 32, k);
    ww9 = oload(Wp, 9 * 32, k);   ww10 = oload(Wp, 10 * 32, k);
    ww11 = oload(Wp, 11 * 32, k); ww12 = oload(Wp, 12 * 32, k);
    ww13 = oload(Wp, 13 * 32, k); ww14 = oload(Wp, 14 * 32, k);
    ww15 = oload(Wp, 15 * 32, k); ww0 = oload(Wp, 16 * 32, k);

    unsigned long long mSC_lo = __ballot((SCc & 1u) != 0u);
    unsigned long long mSA_lo = __ballot((SA & 1u) != 0u);
    unsigned long long mSA_hi = __ballot((SA >> 31) != 0u);
    unsigned int rtC = ((((unsigned int)(mSC_lo >> 1)) >> k) & 1u) << 31;
    unsigned int rxC = SCc | (SCc >> 1) | rtC;
    unsigned int rtA0 = ((((unsigned int)(mSA_lo >> 1)) >> k) & 1u) << 31;
    unsigned int rxA = SA | (SA >> 1) | rtA0;          // Rx(S_2), carried forward
    unsigned int ltA = (((unsigned int)(mSA_hi << 1)) >> k) & 1u;
    unsigned int hxA = rxA | (SA << 1) | ltA;
    unsigned int STAT = rxC | hxA;
    unsigned int prevU = 0u, crp = 0u;

    #pragma unroll 1
    for (int b = 0; b < 64; ++b) {
        const int base = 1 + b * 16;
        TRACK_BODY(0,  ss3,  ss2,  ww1)
        TRACK_BODY(1,  ss4,  ss3,  ww2)
        TRACK_BODY(2,  ss5,  ss4,  ww3)
        TRACK_BODY(3,  ss6,  ss5,  ww4)
        TRACK_BODY(4,  ss7,  ss6,  ww5)
        TRACK_BODY(5,  ss8,  ss7,  ww6)
        TRACK_BODY(6,  ss9,  ss8,  ww7)
        TRACK_BODY(7,  ss10, ss9,  ww8)
        TRACK_BODY(8,  ss11, ss10, ww9)
        TRACK_BODY(9,  ss12, ss11, ww10)
        TRACK_BODY(10, ss13, ss12, ww11)
        TRACK_BODY(11, ss14, ss13, ww12)
        TRACK_BODY(12, ss15, ss14, ww13)
        TRACK_BODY(13, ss0,  ss15, ww14)
        TRACK_BODY(14, ss1,  ss0,  ww15)
        TRACK_BODY(15, ss2,  ss1,  ww0)
    }
}

// ---------------- Stage 5: unpack bits -> float ----------------
__global__ void k_unpack(const unsigned int* __restrict__ Sp,
                         float* __restrict__ out) {
    int idx = blockIdx.x * blockDim.x + threadIdx.x;
    if (idx >= NPIX) return;
    out[idx] = ((Sp[idx >> 5] >> (idx & 31)) & 1u) ? 1.f : 0.f;
}

extern "C" void kernel_launch(void* const* d_in, const int* in_sizes, int n_in,
                              void* d_out, int out_size, void* d_ws, size_t ws_size,
                              hipStream_t stream) {
    const float* x = (const float*)d_in[0];
    float* out = (float*)d_out;
    char* ws = (char*)d_ws;

    unsigned long long* Sp = (unsigned long long*)(ws);
    unsigned long long* Wp = (unsigned long long*)(ws + 128u * 1024u);

    k_fused<<<1024, 256, 0, stream>>>(x, Sp, Wp);
    k_track<<<1, 64, 0, stream>>>((unsigned int*)Sp, (const unsigned int*)Wp);
    k_unpack<<<4096, 256, 0, stream>>>((const unsigned int*)Sp, out);
}